// Round 2
// baseline (124.911 us; speedup 1.0000x reference)
//
#include <hip/hip_runtime.h>

namespace {
constexpr int BB = 2;
constexpr int NN = 50000;
constexpr int KK = 16;
constexpr int CI = 64;
constexpr int CO = 32;
constexpr int MM = 4;
constexpr int BN = BB * NN;            // 100000 nodes total
constexpr int WPB = 4;                 // waves per block
constexpr int NODE_GROUPS = BN / WPB;  // 25000
}

// K1: ux[bn][m] = u[m]·x[bn], vx[bn][m] = v[m]·x[bn]
__global__ __launch_bounds__(256) void k_uxvx(
    const float* __restrict__ x, const float* __restrict__ u,
    const float* __restrict__ v, float* __restrict__ ux,
    float* __restrict__ vx) {
  int idx = blockIdx.x * 256 + threadIdx.x;
  if (idx >= BN) return;
  const float4* xr = (const float4*)(x + (size_t)idx * CI);
  float su[MM] = {0.f, 0.f, 0.f, 0.f};
  float sv[MM] = {0.f, 0.f, 0.f, 0.f};
#pragma unroll
  for (int t = 0; t < CI / 4; ++t) {
    float4 xv = xr[t];
#pragma unroll
    for (int m = 0; m < MM; ++m) {
      float4 uv = *(const float4*)(u + m * CI + t * 4);
      float4 vv = *(const float4*)(v + m * CI + t * 4);
      su[m] += uv.x * xv.x + uv.y * xv.y + uv.z * xv.z + uv.w * xv.w;
      sv[m] += vv.x * xv.x + vv.y * xv.y + vv.z * xv.z + vv.w * xv.w;
    }
  }
  ((float4*)ux)[idx] = make_float4(su[0], su[1], su[2], su[3]);
  ((float4*)vx)[idx] = make_float4(sv[0], sv[1], sv[2], sv[3]);
}

// K2: one wave per node. lane = channel for gather/accumulate;
//     lane = (o, half-of-m) for the 32x256 output matmul from LDS.
__global__ __launch_bounds__(256) void k_main(
    const float* __restrict__ x, const int* __restrict__ adj,
    const float* __restrict__ weight, const float* __restrict__ bias,
    const float* __restrict__ cvec, const float* __restrict__ ux,
    const float* __restrict__ vx, float* __restrict__ out) {
  // stride 68: lane o's float4 slot t4 hits bank-group (o + t4) % 8 ->
  // each consecutive-8-lane group is a bank permutation. NO extra rotation.
  __shared__ float w_lds[MM][CO][CI + 4];
  __shared__ float q_lds[WPB][64];
  __shared__ float t_lds[WPB][MM][CI];

  const int tid = threadIdx.x;
  const int lane = tid & 63;
  const int wv = tid >> 6;

  // stage weight[m][o][c] -> LDS, vectorized (once per persistent block)
#pragma unroll
  for (int i = 0; i < (MM * CO * CI) / (256 * 4); ++i) {
    int g = (i * 256 + tid) * 4;
    float4 w4 = *(const float4*)(weight + g);
    *(float4*)&w_lds[g >> 11][(g >> 6) & (CO - 1)][g & (CI - 1)] = w4;
  }
  __syncthreads();

  const int k4 = lane >> 2;   // neighbor slot for softmax phase
  const int m4 = lane & 3;    // mixture index for softmax phase
  const int o = lane & 31;    // output channel for matmul phase
  const int h = lane >> 5;    // m-half for matmul phase
  const float cm = cvec[m4];
  const float bo = bias[o];
  const float4* qv4 = (const float4*)&q_lds[wv][0];

  // software prefetch of next iteration's adj / per-lane adj scalar / ux
  int4 A0, A1, A2, A3;
  int a_pref;
  float uxv_pref;
  {
    const int bn = blockIdx.x * WPB + wv;
    const int4* ap = (const int4*)(adj + (size_t)bn * KK);
    A0 = ap[0]; A1 = ap[1]; A2 = ap[2]; A3 = ap[3];
    a_pref = adj[(size_t)bn * KK + k4];
    uxv_pref = ux[(size_t)bn * MM + m4];
  }

  for (int g = blockIdx.x; g < NODE_GROUPS; g += gridDim.x) {
    const int bn = g * WPB + wv;
    const int b = (bn >= NN) ? 1 : 0;
    const float* xb = x + (size_t)b * NN * CI;

    int4 C0 = A0, C1 = A1, C2 = A2, C3 = A3;
    const int a = a_pref;
    const float uxv = uxv_pref;

    // issue next iteration's loads right away (latency hidden under compute)
    const int gn = g + gridDim.x;
    if (gn < NODE_GROUPS) {
      const int bnn = gn * WPB + wv;
      const int4* ap = (const int4*)(adj + (size_t)bnn * KK);
      A0 = ap[0]; A1 = ap[1]; A2 = ap[2]; A3 = ap[3];
      a_pref = adj[(size_t)bnn * KK + k4];
      uxv_pref = ux[(size_t)bnn * MM + m4];
    }

    // issue the 16 neighbor-row gathers early (coalesced 256B each)
    int rows[KK];
    {
      int tmp[KK] = {C0.x, C0.y, C0.z, C0.w, C1.x, C1.y, C1.z, C1.w,
                     C2.x, C2.y, C2.z, C2.w, C3.x, C3.y, C3.z, C3.w};
#pragma unroll
      for (int k = 0; k < KK; ++k) rows[k] = max(tmp[k], 1) - 1;
    }
    float xg[KK];
#pragma unroll
    for (int k = 0; k < KK; ++k) xg[k] = xb[(size_t)rows[k] * CI + lane];

    // degree normalization (wave-uniform)
    int deg = 0;
    deg += (C0.x != 0) + (C0.y != 0) + (C0.z != 0) + (C0.w != 0);
    deg += (C1.x != 0) + (C1.y != 0) + (C1.z != 0) + (C1.w != 0);
    deg += (C2.x != 0) + (C2.y != 0) + (C2.z != 0) + (C2.w != 0);
    deg += (C3.x != 0) + (C3.y != 0) + (C3.z != 0) + (C3.w != 0);
    const float inv_deg = (deg > 0) ? 1.0f / (float)deg : 0.0f;

    // softmax gate q[k][m], lane = k*4+m; zero q for empty slots
    float vg = 0.f;
    if (a != 0) vg = vx[((size_t)b * NN + (a - 1)) * MM + m4];
    float logit = vg + uxv + cm;
    float mx = fmaxf(logit, __shfl_xor(logit, 1));
    mx = fmaxf(mx, __shfl_xor(mx, 2));
    float e = __expf(logit - mx);
    float s = e + __shfl_xor(e, 1);
    s += __shfl_xor(s, 2);
    float q = (a != 0) ? (e / s) : 0.f;
    q_lds[wv][lane] = q;

    // t[m][c] = sum_k q[k][m] * x_nbr[k][c]   (lane = c)
    float t0 = 0.f, t1 = 0.f, t2 = 0.f, t3 = 0.f;
#pragma unroll
    for (int k = 0; k < KK; ++k) {
      float4 qv = qv4[k];  // broadcast read, immediate offset
      t0 += qv.x * xg[k];
      t1 += qv.y * xg[k];
      t2 += qv.z * xg[k];
      t3 += qv.w * xg[k];
    }
    t_lds[wv][0][lane] = t0;
    t_lds[wv][1][lane] = t1;
    t_lds[wv][2][lane] = t2;
    t_lds[wv][3][lane] = t3;
    // same-wave DS ops are in-order: no barrier needed (per-wave LDS slices)

    // out[o] = sum_{m,c} w[m][o][c] * t[m][c]; each lane does 2 of 4 m's
    float a0 = 0.f, a1 = 0.f, a2 = 0.f, a3 = 0.f;
#pragma unroll
    for (int mm = 0; mm < 2; ++mm) {
      const float* wrow = &w_lds[2 * h + mm][o][0];
      const float* trow = &t_lds[wv][2 * h + mm][0];
#pragma unroll
      for (int t4 = 0; t4 < CI / 4; ++t4) {
        float4 wvv = *(const float4*)(wrow + 4 * t4);  // imm-offset ds_read_b128
        float4 tv = *(const float4*)(trow + 4 * t4);   // broadcast
        a0 += wvv.x * tv.x;
        a1 += wvv.y * tv.y;
        a2 += wvv.z * tv.z;
        a3 += wvv.w * tv.w;
      }
    }
    float acc = (a0 + a1) + (a2 + a3);
    acc += __shfl_xor(acc, 32);  // combine the two m-halves
    if (lane < 32) out[(size_t)bn * CO + o] = acc * inv_deg + bo;
  }
}

extern "C" void kernel_launch(void* const* d_in, const int* in_sizes, int n_in,
                              void* d_out, int out_size, void* d_ws,
                              size_t ws_size, hipStream_t stream) {
  const float* x = (const float*)d_in[0];
  const int* adj = (const int*)d_in[1];
  const float* weight = (const float*)d_in[2];
  const float* bias = (const float*)d_in[3];
  const float* u = (const float*)d_in[4];
  const float* v = (const float*)d_in[5];
  const float* cvec = (const float*)d_in[6];
  float* out = (float*)d_out;

  float* ux = (float*)d_ws;                 // BN*4 floats
  float* vx = ux + (size_t)BN * MM;         // BN*4 floats (3.2 MB total)

  k_uxvx<<<(BN + 255) / 256, 256, 0, stream>>>(x, u, v, ux, vx);
  k_main<<<1024, 256, 0, stream>>>(x, adj, weight, bias, cvec, ux, vx, out);
}

// Round 3
// 84.973 us; speedup vs baseline: 1.4700x; 1.4700x over previous
//
#include <hip/hip_runtime.h>

namespace {
constexpr int BB = 2;
constexpr int NN = 50000;
constexpr int KK = 16;
constexpr int CI = 64;
constexpr int CO = 32;
constexpr int MM = 4;
constexpr int BN = BB * NN;  // 100000 nodes
}

typedef __attribute__((ext_vector_type(8))) short short8v;
typedef __attribute__((ext_vector_type(4))) float float4v;

__device__ __forceinline__ unsigned short bf16r(float f) {
  unsigned int u = __float_as_uint(f);
  u += 0x7FFFu + ((u >> 16) & 1u);
  return (unsigned short)(u >> 16);
}

// K1: ux[bn][m] = u[m]·x[bn], vx[bn][m] = v[m]·x[bn]
__global__ __launch_bounds__(256) void k_uxvx(
    const float* __restrict__ x, const float* __restrict__ u,
    const float* __restrict__ v, float* __restrict__ ux,
    float* __restrict__ vx) {
  int idx = blockIdx.x * 256 + threadIdx.x;
  if (idx >= BN) return;
  const float4* xr = (const float4*)(x + (size_t)idx * CI);
  float su[MM] = {0.f, 0.f, 0.f, 0.f};
  float sv[MM] = {0.f, 0.f, 0.f, 0.f};
#pragma unroll
  for (int t = 0; t < CI / 4; ++t) {
    float4 xv = xr[t];
#pragma unroll
    for (int m = 0; m < MM; ++m) {
      float4 uv = *(const float4*)(u + m * CI + t * 4);
      float4 vv = *(const float4*)(v + m * CI + t * 4);
      su[m] += uv.x * xv.x + uv.y * xv.y + uv.z * xv.z + uv.w * xv.w;
      sv[m] += vv.x * xv.x + vv.y * xv.y + vv.z * xv.z + vv.w * xv.w;
    }
  }
  ((float4*)ux)[idx] = make_float4(su[0], su[1], su[2], su[3]);
  ((float4*)vx)[idx] = make_float4(sv[0], sv[1], sv[2], sv[3]);
}

// K2: wx[n][j] = sum_c x[n][c] * W[m][o][c],  j = o*4 + m, bf16 output.
// MFMA 16x16x32_bf16: A row = lane&15, k = (lane>>4)*8+e; B col = lane&15,
// k = (lane>>4)*8+e; D col = lane&15, row = (lane>>4)*4+reg.
__global__ __launch_bounds__(256) void k_wx(
    const float* __restrict__ x, const float* __restrict__ weight,
    unsigned short* __restrict__ wx) {
  __shared__ float wt[CI][129];  // wt[c][j], pad to 129 -> conflict-free
  const int tid = threadIdx.x;
#pragma unroll
  for (int i = 0; i < (MM * CO * CI) / 256; ++i) {
    int idx = i * 256 + tid;
    int m = idx >> 11;
    int o = (idx >> 6) & 31;
    int c = idx & 63;
    wt[c][o * 4 + m] = weight[idx];
  }
  __syncthreads();

  const int lane = tid & 63;
  const int wv = tid >> 6;
  const int col = lane & 15;
  const int krow = lane >> 4;

  short8v bfrag[8][2];
#pragma unroll
  for (int nt = 0; nt < 8; ++nt)
#pragma unroll
    for (int ks = 0; ks < 2; ++ks)
#pragma unroll
      for (int e = 0; e < 8; ++e)
        bfrag[nt][ks][e] =
            (short)bf16r(wt[ks * 32 + krow * 8 + e][nt * 16 + col]);

  const float4v zero = {0.f, 0.f, 0.f, 0.f};
  const int nw = gridDim.x * 4;
  for (int t = blockIdx.x * 4 + wv; t < BN / 16; t += nw) {
    const int n0 = t * 16;
    const float* xp = x + (size_t)(n0 + col) * CI + krow * 8;
    short8v afrag[2];
#pragma unroll
    for (int ks = 0; ks < 2; ++ks) {
      float4 lo = *(const float4*)(xp + ks * 32);
      float4 hi = *(const float4*)(xp + ks * 32 + 4);
      afrag[ks][0] = (short)bf16r(lo.x);
      afrag[ks][1] = (short)bf16r(lo.y);
      afrag[ks][2] = (short)bf16r(lo.z);
      afrag[ks][3] = (short)bf16r(lo.w);
      afrag[ks][4] = (short)bf16r(hi.x);
      afrag[ks][5] = (short)bf16r(hi.y);
      afrag[ks][6] = (short)bf16r(hi.z);
      afrag[ks][7] = (short)bf16r(hi.w);
    }
    float4v acc[8];
#pragma unroll
    for (int nt = 0; nt < 8; ++nt) {
      acc[nt] = zero;
      acc[nt] = __builtin_amdgcn_mfma_f32_16x16x32_bf16(afrag[0], bfrag[nt][0],
                                                        acc[nt], 0, 0, 0);
      acc[nt] = __builtin_amdgcn_mfma_f32_16x16x32_bf16(afrag[1], bfrag[nt][1],
                                                        acc[nt], 0, 0, 0);
    }
#pragma unroll
    for (int nt = 0; nt < 8; ++nt)
#pragma unroll
      for (int ri = 0; ri < 4; ++ri)
        wx[(size_t)(n0 + krow * 4 + ri) * 128 + nt * 16 + col] =
            bf16r(acc[nt][ri]);
  }
}

// K3: one wave per node. out[o] = sum_{k,m} q[k,m] * wx[nbr_k][o*4+m].
// Lane holds dword = wx elems (4o+2h, 4o+2h+1) with o=lane>>1, h=lane&1.
__global__ __launch_bounds__(256) void k_gather(
    const unsigned int* __restrict__ wx, const int* __restrict__ adj,
    const float* __restrict__ bias, const float* __restrict__ cvec,
    const float* __restrict__ ux, const float* __restrict__ vx,
    float* __restrict__ out) {
  __shared__ float q_lds[4][64];
  const int tid = threadIdx.x;
  const int lane = tid & 63;
  const int wv = tid >> 6;
  const int m4 = lane & 3;
  const int h = lane & 1;
  const int o = lane >> 1;
  const float cm = cvec[m4];
  const float bo = bias[o];
  const float2* qp = (const float2*)&q_lds[wv][0];

  for (int bn = blockIdx.x * 4 + wv; bn < BN; bn += gridDim.x * 4) {
    const int b = (bn >= NN) ? 1 : 0;
    const int adjv = adj[(size_t)bn * KK + (lane & 15)];
    const int a_s = __shfl(adjv, lane >> 2);

    // 16 row gathers; row index via readlane -> SGPR, saddr-form loads
    unsigned int gv[KK];
    const unsigned int vbase = (b ? (unsigned)NN * 64u : 0u) + (unsigned)lane;
#pragma unroll
    for (int k = 0; k < KK; ++k) {
      int ak = __builtin_amdgcn_readlane(adjv, k);
      unsigned rk = (unsigned)(ak > 0 ? ak - 1 : 0);
      gv[k] = wx[vbase + rk * 64u];
    }

    // degree + softmax gate (no max-sub: |logit| << 80, fp32 exp safe)
    unsigned long long msk = __ballot(adjv != 0);
    int deg = __popcll(msk & 0xFFFFull);
    float inv_deg = deg ? __builtin_amdgcn_rcpf((float)deg) : 0.f;
    float vg = 0.f;
    if (a_s != 0) vg = vx[((size_t)b * NN + (a_s - 1)) * MM + m4];
    float logit = vg + ux[(size_t)bn * MM + m4] + cm;
    float e = __expf(logit);
    float s = e + __shfl_xor(e, 1);
    s += __shfl_xor(s, 2);
    float q = (a_s != 0) ? e * __builtin_amdgcn_rcpf(s) : 0.f;
    q_lds[wv][lane] = q;  // same-wave write->read, no barrier needed

    float acc0 = 0.f, acc1 = 0.f;
#pragma unroll
    for (int k = 0; k < KK; ++k) {
      float2 q2 = qp[k * 2 + h];  // broadcast b64, 2 addrs -> conflict-free
      float wlo = __uint_as_float(gv[k] << 16);
      float whi = __uint_as_float(gv[k] & 0xFFFF0000u);
      acc0 = fmaf(q2.x, wlo, acc0);
      acc1 = fmaf(q2.y, whi, acc1);
    }
    float acc = acc0 + acc1;
    acc += __shfl_xor(acc, 1);
    if (h == 0) out[(size_t)bn * CO + o] = acc * inv_deg + bo;
  }
}

// Fallback (ws too small): round-1 all-fp32 path.
__global__ __launch_bounds__(256) void k_main_old(
    const float* __restrict__ x, const int* __restrict__ adj,
    const float* __restrict__ weight, const float* __restrict__ bias,
    const float* __restrict__ cvec, const float* __restrict__ ux,
    const float* __restrict__ vx, float* __restrict__ out) {
  __shared__ float w_lds[MM][CO][CI + 4];
  __shared__ float q_lds[4][64];
  __shared__ float t_lds[4][MM][CI];
  const int tid = threadIdx.x;
  const int lane = tid & 63;
  const int wv = tid >> 6;
#pragma unroll
  for (int i = 0; i < (MM * CO * CI) / 256; ++i) {
    int g = i * 256 + tid;
    w_lds[g >> 11][(g >> 6) & (CO - 1)][g & (CI - 1)] = weight[g];
  }
  __syncthreads();
  const int k4 = lane >> 2;
  const int m4 = lane & 3;
  const int o = lane & 31;
  const int hh = lane >> 5;
  const float cm = cvec[m4];
  const float bo = bias[o];
  for (int g = blockIdx.x; g < BN / 4; g += gridDim.x) {
    const int bn = g * 4 + wv;
    const int b = (bn >= NN) ? 1 : 0;
    const int* adjp = adj + (size_t)bn * KK;
    const float* xb = x + (size_t)b * NN * CI;
    int4 A[4];
#pragma unroll
    for (int i = 0; i < 4; ++i) A[i] = ((const int4*)adjp)[i];
    int deg = 0;
#pragma unroll
    for (int i = 0; i < 4; ++i)
      deg += (A[i].x != 0) + (A[i].y != 0) + (A[i].z != 0) + (A[i].w != 0);
    const float inv_deg = (deg > 0) ? 1.0f / (float)deg : 0.0f;
    int a = adjp[k4];
    float vg = 0.f;
    if (a != 0) vg = vx[((size_t)b * NN + (a - 1)) * MM + m4];
    float logit = vg + ux[(size_t)bn * MM + m4] + cm;
    float mx = fmaxf(logit, __shfl_xor(logit, 1));
    mx = fmaxf(mx, __shfl_xor(mx, 2));
    float e = __expf(logit - mx);
    float s = e + __shfl_xor(e, 1);
    s += __shfl_xor(s, 2);
    q_lds[wv][lane] = (a != 0) ? (e / s) : 0.f;
    int rows[KK];
    {
      int tmp[KK] = {A[0].x, A[0].y, A[0].z, A[0].w, A[1].x, A[1].y,
                     A[1].z, A[1].w, A[2].x, A[2].y, A[2].z, A[2].w,
                     A[3].x, A[3].y, A[3].z, A[3].w};
#pragma unroll
      for (int k = 0; k < KK; ++k) rows[k] = max(tmp[k], 1) - 1;
    }
    float xg[KK];
#pragma unroll
    for (int k = 0; k < KK; ++k) xg[k] = xb[(size_t)rows[k] * CI + lane];
    float t0 = 0.f, t1 = 0.f, t2 = 0.f, t3 = 0.f;
#pragma unroll
    for (int k = 0; k < KK; ++k) {
      float4 qv = *(const float4*)&q_lds[wv][k * 4];
      t0 += qv.x * xg[k];
      t1 += qv.y * xg[k];
      t2 += qv.z * xg[k];
      t3 += qv.w * xg[k];
    }
    t_lds[wv][0][lane] = t0;
    t_lds[wv][1][lane] = t1;
    t_lds[wv][2][lane] = t2;
    t_lds[wv][3][lane] = t3;
    float a0 = 0.f, a1 = 0.f, a2 = 0.f, a3 = 0.f;
#pragma unroll
    for (int mm = 0; mm < 2; ++mm) {
      const float* wrow = &w_lds[2 * hh + mm][o][0];
      const float* trow = &t_lds[wv][2 * hh + mm][0];
#pragma unroll
      for (int t4 = 0; t4 < CI / 4; ++t4) {
        float4 wvv = *(const float4*)(wrow + 4 * t4);
        float4 tv = *(const float4*)(trow + 4 * t4);
        a0 += wvv.x * tv.x;
        a1 += wvv.y * tv.y;
        a2 += wvv.z * tv.z;
        a3 += wvv.w * tv.w;
      }
    }
    float acc = (a0 + a1) + (a2 + a3);
    acc += __shfl_xor(acc, 32);
    if (lane < 32) out[(size_t)bn * CO + o] = acc * inv_deg + bo;
  }
}

extern "C" void kernel_launch(void* const* d_in, const int* in_sizes, int n_in,
                              void* d_out, int out_size, void* d_ws,
                              size_t ws_size, hipStream_t stream) {
  const float* x = (const float*)d_in[0];
  const int* adj = (const int*)d_in[1];
  const float* weight = (const float*)d_in[2];
  const float* bias = (const float*)d_in[3];
  const float* u = (const float*)d_in[4];
  const float* v = (const float*)d_in[5];
  const float* cvec = (const float*)d_in[6];
  float* out = (float*)d_out;

  float* ux = (float*)d_ws;               // BN*4 f32
  float* vx = ux + (size_t)BN * MM;       // BN*4 f32
  const size_t base = (size_t)BN * MM * 2 * sizeof(float);        // 3.2 MB
  const size_t need = base + (size_t)BN * 128 * sizeof(unsigned short);

  k_uxvx<<<(BN + 255) / 256, 256, 0, stream>>>(x, u, v, ux, vx);
  if (ws_size >= need) {
    unsigned short* wxb = (unsigned short*)((char*)d_ws + base);
    k_wx<<<512, 256, 0, stream>>>(x, weight, wxb);
    k_gather<<<2048, 256, 0, stream>>>((const unsigned int*)wxb, adj, bias,
                                       cvec, ux, vx, out);
  } else {
    k_main_old<<<1024, 256, 0, stream>>>(x, adj, weight, bias, cvec, ux, vx,
                                         out);
  }
}

// Round 4
// 74.879 us; speedup vs baseline: 1.6682x; 1.1348x over previous
//
#include <hip/hip_runtime.h>

namespace {
constexpr int BB = 2;
constexpr int NN = 50000;
constexpr int KK = 16;
constexpr int CI = 64;
constexpr int CO = 32;
constexpr int MM = 4;
constexpr int BN = BB * NN;  // 100000 nodes
}

typedef __attribute__((ext_vector_type(8))) short short8v;
typedef __attribute__((ext_vector_type(4))) float float4v;

__device__ __forceinline__ unsigned short bf16r(float f) {
  unsigned int u = __float_as_uint(f);
  u += 0x7FFFu + ((u >> 16) & 1u);
  return (unsigned short)(u >> 16);
}

// K1 (fallback only): ux[bn][m] = u[m]·x[bn], vx[bn][m] = v[m]·x[bn]
__global__ __launch_bounds__(256) void k_uxvx(
    const float* __restrict__ x, const float* __restrict__ u,
    const float* __restrict__ v, float* __restrict__ ux,
    float* __restrict__ vx) {
  int idx = blockIdx.x * 256 + threadIdx.x;
  if (idx >= BN) return;
  const float4* xr = (const float4*)(x + (size_t)idx * CI);
  float su[MM] = {0.f, 0.f, 0.f, 0.f};
  float sv[MM] = {0.f, 0.f, 0.f, 0.f};
#pragma unroll
  for (int t = 0; t < CI / 4; ++t) {
    float4 xv = xr[t];
#pragma unroll
    for (int m = 0; m < MM; ++m) {
      float4 uv = *(const float4*)(u + m * CI + t * 4);
      float4 vv = *(const float4*)(v + m * CI + t * 4);
      su[m] += uv.x * xv.x + uv.y * xv.y + uv.z * xv.z + uv.w * xv.w;
      sv[m] += vv.x * xv.x + vv.y * xv.y + vv.z * xv.z + vv.w * xv.w;
    }
  }
  ((float4*)ux)[idx] = make_float4(su[0], su[1], su[2], su[3]);
  ((float4*)vx)[idx] = make_float4(sv[0], sv[1], sv[2], sv[3]);
}

// K2: wx[n][j] = sum_c x[n][c] * W[m][o][c], j = o*4+m (bf16), FUSED with
// ux/vx = x·[u;v]^T via one extra MFMA B-fragment.
// MFMA 16x16x32_bf16: A row=lane&15, k=(lane>>4)*8+e; B col=lane&15, same k;
// D col=lane&15, row=(lane>>4)*4+reg.
__global__ __launch_bounds__(256) void k_wx(
    const float* __restrict__ x, const float* __restrict__ weight,
    const float* __restrict__ u, const float* __restrict__ v,
    unsigned short* __restrict__ wx, float* __restrict__ ux,
    float* __restrict__ vx) {
  __shared__ float wt[CI][129];  // wt[c][j], pad 129 -> conflict-free
  const int tid = threadIdx.x;
#pragma unroll
  for (int i = 0; i < (MM * CO * CI) / 256; ++i) {
    int idx = i * 256 + tid;
    int m = idx >> 11;
    int o = (idx >> 6) & 31;
    int c = idx & 63;
    wt[c][o * 4 + m] = weight[idx];
  }
  __syncthreads();

  const int lane = tid & 63;
  const int wv = tid >> 6;
  const int col = lane & 15;
  const int krow = lane >> 4;

  short8v bfrag[8][2];
#pragma unroll
  for (int nt = 0; nt < 8; ++nt)
#pragma unroll
    for (int ks = 0; ks < 2; ++ks)
#pragma unroll
      for (int e = 0; e < 8; ++e)
        bfrag[nt][ks][e] =
            (short)bf16r(wt[ks * 32 + krow * 8 + e][nt * 16 + col]);

  // B2[k=c][col]: col<4 -> u[col][c]; col<8 -> v[col-4][c]; else 0
  short8v bfrag2[2];
#pragma unroll
  for (int ks = 0; ks < 2; ++ks)
#pragma unroll
    for (int e = 0; e < 8; ++e) {
      int c = ks * 32 + krow * 8 + e;
      float val = (col < 4) ? u[col * CI + c]
                            : ((col < 8) ? v[(col - 4) * CI + c] : 0.f);
      bfrag2[ks][e] = (short)bf16r(val);
    }

  const float4v zero = {0.f, 0.f, 0.f, 0.f};
  const int nw = gridDim.x * 4;
  for (int t = blockIdx.x * 4 + wv; t < BN / 16; t += nw) {
    const int n0 = t * 16;
    const float* xp = x + (size_t)(n0 + col) * CI + krow * 8;
    short8v afrag[2];
#pragma unroll
    for (int ks = 0; ks < 2; ++ks) {
      float4 lo = *(const float4*)(xp + ks * 32);
      float4 hi = *(const float4*)(xp + ks * 32 + 4);
      afrag[ks][0] = (short)bf16r(lo.x);
      afrag[ks][1] = (short)bf16r(lo.y);
      afrag[ks][2] = (short)bf16r(lo.z);
      afrag[ks][3] = (short)bf16r(lo.w);
      afrag[ks][4] = (short)bf16r(hi.x);
      afrag[ks][5] = (short)bf16r(hi.y);
      afrag[ks][6] = (short)bf16r(hi.z);
      afrag[ks][7] = (short)bf16r(hi.w);
    }
    float4v acc[8];
#pragma unroll
    for (int nt = 0; nt < 8; ++nt) {
      acc[nt] = zero;
      acc[nt] = __builtin_amdgcn_mfma_f32_16x16x32_bf16(afrag[0], bfrag[nt][0],
                                                        acc[nt], 0, 0, 0);
      acc[nt] = __builtin_amdgcn_mfma_f32_16x16x32_bf16(afrag[1], bfrag[nt][1],
                                                        acc[nt], 0, 0, 0);
    }
    float4v acc2 = zero;
    acc2 = __builtin_amdgcn_mfma_f32_16x16x32_bf16(afrag[0], bfrag2[0], acc2,
                                                   0, 0, 0);
    acc2 = __builtin_amdgcn_mfma_f32_16x16x32_bf16(afrag[1], bfrag2[1], acc2,
                                                   0, 0, 0);
#pragma unroll
    for (int nt = 0; nt < 8; ++nt)
#pragma unroll
      for (int ri = 0; ri < 4; ++ri)
        wx[(size_t)(n0 + krow * 4 + ri) * 128 + nt * 16 + col] =
            bf16r(acc[nt][ri]);
#pragma unroll
    for (int ri = 0; ri < 4; ++ri) {
      int node = n0 + krow * 4 + ri;
      if (col < 4)
        ux[(size_t)node * MM + col] = acc2[ri];
      else if (col < 8)
        vx[(size_t)node * MM + (col - 4)] = acc2[ri];
    }
  }
}

// K3: one wave per node-PAIR. Half-wave nn = lane>>5 owns node bn0+nn.
// out[o] = sum_{k,m} q[k,m] * wx[nbr_k][o*4+m]; lane holds dwords 2o,2o+1.
__global__ __launch_bounds__(256, 6) void k_gather(
    const unsigned int* __restrict__ wx, const int* __restrict__ adj,
    const float* __restrict__ bias, const float* __restrict__ cvec,
    const float* __restrict__ ux, const float* __restrict__ vx,
    float* __restrict__ out) {
  __shared__ float q_lds[4][2][64];
  const int tid = threadIdx.x;
  const int lane = tid & 63;
  const int wv = tid >> 6;
  const int m4 = lane & 3;
  const int k4 = lane >> 2;  // 0..15
  const int o = lane & 31;
  const int nn = lane >> 5;  // node of pair
  const float cm = cvec[m4];
  const float bo = bias[o];

  // XCD-aware batch partition: XCDs 0-3 -> batch 0, 4-7 -> batch 1
  const int xcd = blockIdx.x & 7;
  const int b = xcd >> 2;
  const int wb = ((blockIdx.x >> 3) << 2) | (xcd & 3);
  const unsigned int* wxb = wx + (size_t)b * NN * 64;
  const float* vxb = vx + (size_t)b * NN * MM;
  constexpr int PAIRS = NN / 2;  // 25000
  const int wstride = (gridDim.x >> 1) * 4;

  const int p0 = wb * 4 + wv;
  int av = 0;
  if (p0 < PAIRS)
    av = adj[((size_t)b * NN + 2 * (size_t)p0) * KK + (lane & 31)];

  for (int p = p0; p < PAIRS; p += wstride) {
    const int bn0 = b * NN + 2 * p;
    const int av_c = av;

    // softmax-side gathers first (they feed the longest dependency chain)
    const int as0 = __shfl(av_c, k4);
    const int as1 = __shfl(av_c, 16 + k4);
    float vg0 = vxb[(size_t)(max(as0, 1) - 1) * MM + m4];
    float vg1 = vxb[(size_t)(max(as1, 1) - 1) * MM + m4];
    float ux0 = ux[(size_t)bn0 * MM + m4];
    float ux1 = ux[(size_t)bn0 * MM + MM + m4];

    const unsigned long long msk = __ballot(av_c != 0);

    // 16 x dwordx2 wx gathers (lanes 0-31: node0 row, 32-63: node1 row)
    uint2 gv[KK];
#pragma unroll
    for (int k = 0; k < KK; ++k) {
      int r0 = __builtin_amdgcn_readlane(av_c, k);
      int r1 = __builtin_amdgcn_readlane(av_c, 16 + k);
      int rs = nn ? r1 : r0;
      unsigned rk = (unsigned)(rs > 0 ? rs - 1 : 0);
      gv[k] = *(const uint2*)(wxb + (size_t)rk * 64u + 2u * (unsigned)o);
    }

    // prefetch next pair's adjacency (hides under softmax + FMA)
    const int pn = p + wstride;
    if (pn < PAIRS)
      av = adj[((size_t)b * NN + 2 * (size_t)pn) * KK + (lane & 31)];

    // softmax for both nodes (|logit| small -> no max subtraction)
    const int deg0 = __popcll(msk & 0xFFFFull);
    const int deg1 = __popcll(msk & 0xFFFF0000ull);
    const float inv0 = deg0 ? __builtin_amdgcn_rcpf((float)deg0) : 0.f;
    const float inv1 = deg1 ? __builtin_amdgcn_rcpf((float)deg1) : 0.f;
    float e0 = __expf(vg0 + ux0 + cm);
    float e1 = __expf(vg1 + ux1 + cm);
    float s0 = e0 + __shfl_xor(e0, 1);
    s0 += __shfl_xor(s0, 2);
    float s1 = e1 + __shfl_xor(e1, 1);
    s1 += __shfl_xor(s1, 2);
    q_lds[wv][0][lane] = (as0 != 0) ? e0 * __builtin_amdgcn_rcpf(s0) : 0.f;
    q_lds[wv][1][lane] = (as1 != 0) ? e1 * __builtin_amdgcn_rcpf(s1) : 0.f;
    // same-wave DS write->read is in-order: no barrier needed

    const float4* qp = (const float4*)&q_lds[wv][nn][0];
    float a0 = 0.f, a1 = 0.f, a2 = 0.f, a3 = 0.f;
#pragma unroll
    for (int k = 0; k < KK; ++k) {
      float4 qv = qp[k];  // broadcast per half-wave
      unsigned lo = gv[k].x, hi = gv[k].y;
      a0 = fmaf(qv.x, __uint_as_float(lo << 16), a0);
      a1 = fmaf(qv.y, __uint_as_float(lo & 0xFFFF0000u), a1);
      a2 = fmaf(qv.z, __uint_as_float(hi << 16), a2);
      a3 = fmaf(qv.w, __uint_as_float(hi & 0xFFFF0000u), a3);
    }
    const float acc = (a0 + a1) + (a2 + a3);
    const float invd = nn ? inv1 : inv0;
    // one fully-coalesced 256B store covering both nodes
    out[(size_t)bn0 * CO + lane] = acc * invd + bo;
  }
}

// Fallback (ws too small): round-1 all-fp32 path.
__global__ __launch_bounds__(256) void k_main_old(
    const float* __restrict__ x, const int* __restrict__ adj,
    const float* __restrict__ weight, const float* __restrict__ bias,
    const float* __restrict__ cvec, const float* __restrict__ ux,
    const float* __restrict__ vx, float* __restrict__ out) {
  __shared__ float w_lds[MM][CO][CI + 4];
  __shared__ float q_lds[4][64];
  __shared__ float t_lds[4][MM][CI];
  const int tid = threadIdx.x;
  const int lane = tid & 63;
  const int wv = tid >> 6;
#pragma unroll
  for (int i = 0; i < (MM * CO * CI) / 256; ++i) {
    int g = i * 256 + tid;
    w_lds[g >> 11][(g >> 6) & (CO - 1)][g & (CI - 1)] = weight[g];
  }
  __syncthreads();
  const int k4 = lane >> 2;
  const int m4 = lane & 3;
  const int o = lane & 31;
  const int hh = lane >> 5;
  const float cm = cvec[m4];
  const float bo = bias[o];
  for (int g = blockIdx.x; g < BN / 4; g += gridDim.x) {
    const int bn = g * 4 + wv;
    const int b = (bn >= NN) ? 1 : 0;
    const int* adjp = adj + (size_t)bn * KK;
    const float* xb = x + (size_t)b * NN * CI;
    int4 A[4];
#pragma unroll
    for (int i = 0; i < 4; ++i) A[i] = ((const int4*)adjp)[i];
    int deg = 0;
#pragma unroll
    for (int i = 0; i < 4; ++i)
      deg += (A[i].x != 0) + (A[i].y != 0) + (A[i].z != 0) + (A[i].w != 0);
    const float inv_deg = (deg > 0) ? 1.0f / (float)deg : 0.0f;
    int a = adjp[k4];
    float vg = 0.f;
    if (a != 0) vg = vx[((size_t)b * NN + (a - 1)) * MM + m4];
    float logit = vg + ux[(size_t)bn * MM + m4] + cm;
    float mx = fmaxf(logit, __shfl_xor(logit, 1));
    mx = fmaxf(mx, __shfl_xor(mx, 2));
    float e = __expf(logit - mx);
    float s = e + __shfl_xor(e, 1);
    s += __shfl_xor(s, 2);
    q_lds[wv][lane] = (a != 0) ? (e / s) : 0.f;
    int rows[KK];
    {
      int tmp[KK] = {A[0].x, A[0].y, A[0].z, A[0].w, A[1].x, A[1].y,
                     A[1].z, A[1].w, A[2].x, A[2].y, A[2].z, A[2].w,
                     A[3].x, A[3].y, A[3].z, A[3].w};
#pragma unroll
      for (int k = 0; k < KK; ++k) rows[k] = max(tmp[k], 1) - 1;
    }
    float xg[KK];
#pragma unroll
    for (int k = 0; k < KK; ++k) xg[k] = xb[(size_t)rows[k] * CI + lane];
    float t0 = 0.f, t1 = 0.f, t2 = 0.f, t3 = 0.f;
#pragma unroll
    for (int k = 0; k < KK; ++k) {
      float4 qv = *(const float4*)&q_lds[wv][k * 4];
      t0 += qv.x * xg[k];
      t1 += qv.y * xg[k];
      t2 += qv.z * xg[k];
      t3 += qv.w * xg[k];
    }
    t_lds[wv][0][lane] = t0;
    t_lds[wv][1][lane] = t1;
    t_lds[wv][2][lane] = t2;
    t_lds[wv][3][lane] = t3;
    float a0 = 0.f, a1 = 0.f, a2 = 0.f, a3 = 0.f;
#pragma unroll
    for (int mm = 0; mm < 2; ++mm) {
      const float* wrow = &w_lds[2 * hh + mm][o][0];
      const float* trow = &t_lds[wv][2 * hh + mm][0];
#pragma unroll
      for (int t4 = 0; t4 < CI / 4; ++t4) {
        float4 wvv = *(const float4*)(wrow + 4 * t4);
        float4 tv = *(const float4*)(trow + 4 * t4);
        a0 += wvv.x * tv.x;
        a1 += wvv.y * tv.y;
        a2 += wvv.z * tv.z;
        a3 += wvv.w * tv.w;
      }
    }
    float acc = (a0 + a1) + (a2 + a3);
    acc += __shfl_xor(acc, 32);
    if (lane < 32) out[(size_t)bn * CO + o] = acc * inv_deg + bo;
  }
}

extern "C" void kernel_launch(void* const* d_in, const int* in_sizes, int n_in,
                              void* d_out, int out_size, void* d_ws,
                              size_t ws_size, hipStream_t stream) {
  const float* x = (const float*)d_in[0];
  const int* adj = (const int*)d_in[1];
  const float* weight = (const float*)d_in[2];
  const float* bias = (const float*)d_in[3];
  const float* u = (const float*)d_in[4];
  const float* v = (const float*)d_in[5];
  const float* cvec = (const float*)d_in[6];
  float* out = (float*)d_out;

  float* ux = (float*)d_ws;            // BN*4 f32
  float* vx = ux + (size_t)BN * MM;    // BN*4 f32
  const size_t base = (size_t)BN * MM * 2 * sizeof(float);  // 3.2 MB
  const size_t need = base + (size_t)BN * 128 * sizeof(unsigned short);

  if (ws_size >= need) {
    unsigned short* wxb = (unsigned short*)((char*)d_ws + base);
    k_wx<<<1024, 256, 0, stream>>>(x, weight, u, v, wxb, ux, vx);
    k_gather<<<2048, 256, 0, stream>>>((const unsigned int*)wxb, adj, bias,
                                       cvec, ux, vx, out);
  } else {
    k_uxvx<<<(BN + 255) / 256, 256, 0, stream>>>(x, u, v, ux, vx);
    k_main_old<<<1024, 256, 0, stream>>>(x, adj, weight, bias, cvec, ux, vx,
                                         out);
  }
}